// Round 7
// baseline (407.647 us; speedup 1.0000x reference)
//
#include <hip/hip_runtime.h>

#define N_NODES 100000
#define N_EDGES 3200000
#define N_GRAPHS 2048
#define BSH 6                       // 64 nodes per bucket
#define BSZ 64
#define NB 1563                     // ceil(N_NODES/64)
#define FILL_BLOCKS 512
#define CHUNK 6250                  // N_EDGES / FILL_BLOCKS exactly

// global fp32 fadd (no CAS loop) — ONLY for global pointers
__device__ __forceinline__ void gAtomAdd(float* p, float v) {
  unsafeAtomicAdd(p, v);
}

// ---------- pass 1: per-block bucket histogram + space reservation ----------
__global__ void k_count(const int* __restrict__ dst, int* __restrict__ bcnt,
                        int* __restrict__ blockBase) {
  __shared__ int hist[NB];
  int tid = threadIdx.x, blk = blockIdx.x;
  for (int i = tid; i < NB; i += 256) hist[i] = 0;
  __syncthreads();
  int beg = blk * CHUNK, end = beg + CHUNK;
  for (int e = beg + tid; e < end; e += 256) atomicAdd(&hist[dst[e] >> BSH], 1);
  __syncthreads();
  for (int i = tid; i < NB; i += 256) {
    int h = hist[i];
    if (h) blockBase[blk * NB + i] = atomicAdd(&bcnt[i], h);
  }
}

// ---------- exclusive scan over NB bucket counts (single block, chunked) ----------
__global__ void k_bscan(const int* __restrict__ bcnt, int* __restrict__ boffs) {
  __shared__ int sh[512];
  __shared__ int carry;
  int tid = threadIdx.x;
  if (tid == 0) carry = 0;
  __syncthreads();
  for (int c = 0; c < NB; c += 512) {
    int i = c + tid;
    int v = (i < NB) ? bcnt[i] : 0;
    sh[tid] = v;
    __syncthreads();
    for (int off = 1; off < 512; off <<= 1) {
      int t = (tid >= off) ? sh[tid - off] : 0;
      __syncthreads();
      sh[tid] += t;
      __syncthreads();
    }
    if (i < NB) boffs[i] = carry + sh[tid] - v;
    __syncthreads();
    if (tid == 511) carry += sh[511];
    __syncthreads();
  }
  if (tid == 0) boffs[NB] = N_EDGES;
}

// ---------- pass 2: write packed edges into reserved dense sub-ranges ----------
__global__ void k_fill(const int* __restrict__ src, const int* __restrict__ dst,
                       const int* __restrict__ boffs, const int* __restrict__ blockBase,
                       unsigned* __restrict__ stage) {
  __shared__ int lbase[NB];
  int tid = threadIdx.x, blk = blockIdx.x;
  for (int i = tid; i < NB; i += 256) lbase[i] = boffs[i] + blockBase[blk * NB + i];
  __syncthreads();
  int beg = blk * CHUNK, end = beg + CHUNK;
  for (int e = beg + tid; e < end; e += 256) {
    int d = dst[e], s = src[e];
    int pos = atomicAdd(&lbase[d >> BSH], 1);   // LDS cursor
    stage[pos] = ((unsigned)s << BSH) | (unsigned)(d & (BSZ - 1));
  }
}

// ---------- bucket-local degree -> dinv, xd8 = x*dinv (padded to 8 floats/row) ----------
__global__ void k_prep(const unsigned* __restrict__ stage, const int* __restrict__ boffs,
                       const float* __restrict__ x, float* __restrict__ dinv,
                       float* __restrict__ xd8) {
  __shared__ int cnt[BSZ];
  int b = blockIdx.x, tid = threadIdx.x;
  if (tid < BSZ) cnt[tid] = 0;
  __syncthreads();
  int beg = boffs[b], end = boffs[b + 1];
  for (int k = beg + tid; k < end; k += 256) atomicAdd(&cnt[stage[k] & (BSZ - 1)], 1);
  __syncthreads();
  int node = b * BSZ + tid;
  if (tid < BSZ && node < N_NODES) {
    float di = rsqrtf((float)(cnt[tid] + 1));     // +1 self-loop; always > 0
    dinv[node] = di;
    float r[5];
#pragma unroll
    for (int c = 0; c < 5; c++) r[c] = x[node * 5 + c] * di;
    float4* xv = (float4*)xd8;
    xv[node * 2]     = make_float4(r[0], r[1], r[2], r[3]);
    xv[node * 2 + 1] = make_float4(r[4], 0.f, 0.f, 0.f);   // pad cols 5..7 = 0
  }
}

// ---------- layer-1 aggregation: 8-lane groups, 4-deep gather pipeline ----------
__global__ void k_agg1(const unsigned* __restrict__ stage, const int* __restrict__ boffs,
                       const float* __restrict__ xd8, const float* __restrict__ dinv,
                       const float* __restrict__ W1, const float* __restrict__ b1,
                       const float* __restrict__ W2, float* __restrict__ g2) {
  __shared__ float acc[BSZ * 8];                  // cols 5..7 accumulate pad zeros
  __shared__ float w1[150], bb1[30], w2[240];
  int b = blockIdx.x, tid = threadIdx.x;
  for (int i = tid; i < BSZ * 8; i += 256) acc[i] = 0.f;
  for (int i = tid; i < 150; i += 256) w1[i] = W1[i];
  for (int i = tid; i < 30; i += 256) bb1[i] = b1[i];
  for (int i = tid; i < 240; i += 256) w2[i] = W2[i];
  __syncthreads();
  int beg = boffs[b], end = boffs[b + 1];
  const int G = 32;
  int group = tid >> 3, lane = tid & 7;
  int k = beg + group;
  while (k + 3 * G < end) {                       // 4 independent gathers in flight
    unsigned u0 = stage[k], u1 = stage[k + G], u2 = stage[k + 2 * G], u3 = stage[k + 3 * G];
    float f0 = xd8[(u0 >> BSH) * 8 + lane];
    float f1 = xd8[(u1 >> BSH) * 8 + lane];
    float f2 = xd8[(u2 >> BSH) * 8 + lane];
    float f3 = xd8[(u3 >> BSH) * 8 + lane];
    atomicAdd(&acc[(u0 & (BSZ - 1)) * 8 + lane], f0);
    atomicAdd(&acc[(u1 & (BSZ - 1)) * 8 + lane], f1);
    atomicAdd(&acc[(u2 & (BSZ - 1)) * 8 + lane], f2);
    atomicAdd(&acc[(u3 & (BSZ - 1)) * 8 + lane], f3);
    k += 4 * G;
  }
  while (k < end) {
    unsigned u = stage[k];
    atomicAdd(&acc[(u & (BSZ - 1)) * 8 + lane], xd8[(u >> BSH) * 8 + lane]);
    k += G;
  }
  __syncthreads();
  int node = b * BSZ + tid;
  if (tid < BSZ && node < N_NODES) {
    float di = dinv[node];
    float t[5];
#pragma unroll
    for (int c = 0; c < 5; c++) t[c] = (acc[tid * 8 + c] + xd8[node * 8 + c]) * di;
    float h[30];
#pragma unroll
    for (int j = 0; j < 30; j++) h[j] = bb1[j];
#pragma unroll
    for (int kk = 0; kk < 5; kk++)
#pragma unroll
      for (int j = 0; j < 30; j++) h[j] += t[kk] * w1[kk * 30 + j];
    float g[8] = {0, 0, 0, 0, 0, 0, 0, 0};
#pragma unroll
    for (int j = 0; j < 30; j++) {
      float hj = fmaxf(h[j], 0.f);
#pragma unroll
      for (int c = 0; c < 8; c++) g[c] += hj * w2[j * 8 + c];
    }
    float4* gv = (float4*)g2;
    gv[node * 2]     = make_float4(g[0] * di, g[1] * di, g[2] * di, g[3] * di);
    gv[node * 2 + 1] = make_float4(g[4] * di, g[5] * di, g[6] * di, g[7] * di);
  }
}

// ---------- layer-2 aggregation: 4-deep gather pipeline + fused pooling ----------
__global__ void k_agg2(const unsigned* __restrict__ stage, const int* __restrict__ boffs,
                       const float* __restrict__ g2, const float* __restrict__ dinv,
                       const float* __restrict__ b2, const int* __restrict__ batch,
                       float* __restrict__ gsum) {
  __shared__ float acc[BSZ * 8];
  __shared__ float gpool[BSZ * 8];
  __shared__ float bb2[8];
  __shared__ int batch0s;
  int b = blockIdx.x, tid = threadIdx.x;
  for (int i = tid; i < BSZ * 8; i += 256) { acc[i] = 0.f; gpool[i] = 0.f; }
  if (tid < 8) bb2[tid] = b2[tid];
  if (tid == 0) batch0s = batch[b * BSZ];
  __syncthreads();
  int beg = boffs[b], end = boffs[b + 1];
  const int G = 32;
  int group = tid >> 3, lane = tid & 7;
  int k = beg + group;
  while (k + 3 * G < end) {                       // 4 independent gathers in flight
    unsigned u0 = stage[k], u1 = stage[k + G], u2 = stage[k + 2 * G], u3 = stage[k + 3 * G];
    float f0 = g2[(u0 >> BSH) * 8 + lane];
    float f1 = g2[(u1 >> BSH) * 8 + lane];
    float f2 = g2[(u2 >> BSH) * 8 + lane];
    float f3 = g2[(u3 >> BSH) * 8 + lane];
    atomicAdd(&acc[(u0 & (BSZ - 1)) * 8 + lane], f0);
    atomicAdd(&acc[(u1 & (BSZ - 1)) * 8 + lane], f1);
    atomicAdd(&acc[(u2 & (BSZ - 1)) * 8 + lane], f2);
    atomicAdd(&acc[(u3 & (BSZ - 1)) * 8 + lane], f3);
    k += 4 * G;
  }
  while (k < end) {
    unsigned u = stage[k];
    atomicAdd(&acc[(u & (BSZ - 1)) * 8 + lane], g2[(u >> BSH) * 8 + lane]);
    k += G;
  }
  __syncthreads();
  int node = b * BSZ + tid;
  int batch0 = batch0s;
  if (tid < BSZ && node < N_NODES) {
    float di = dinv[node];
    int goff = batch[node] - batch0;
#pragma unroll
    for (int c = 0; c < 8; c++) {
      float val = di * (g2[node * 8 + c] + acc[tid * 8 + c]) + bb2[c];
      if (goff < BSZ) atomicAdd(&gpool[goff * 8 + c], val);
      else            gAtomAdd(&gsum[batch[node] * 8 + c], val);
    }
  }
  __syncthreads();
  for (int i = tid; i < BSZ * 8; i += 256) {
    int gid = batch0 + (i >> 3);
    float v = gpool[i];
    if (gid < N_GRAPHS && v != 0.f) gAtomAdd(&gsum[gid * 8 + (i & 7)], v);
  }
}

// ---------- epilogue: divide by per-graph node count (binary search, batch sorted) ----------
__global__ void k_final(const float* __restrict__ gsum, const int* __restrict__ batch,
                        float* __restrict__ out) {
  int i = blockIdx.x * 256 + threadIdx.x;
  if (i >= N_GRAPHS * 8) return;
  int g = i >> 3;
  int lo = 0, hi = N_NODES;
  while (lo < hi) { int m = (lo + hi) >> 1; if (batch[m] < g) lo = m + 1; else hi = m; }
  int lo2 = lo, hi2 = N_NODES;
  while (lo2 < hi2) { int m = (lo2 + hi2) >> 1; if (batch[m] <= g) lo2 = m + 1; else hi2 = m; }
  float c = (float)(lo2 - lo);
  out[i] = gsum[i] / fmaxf(c, 1.f);
}

extern "C" void kernel_launch(void* const* d_in, const int* in_sizes, int n_in,
                              void* d_out, int out_size, void* d_ws, size_t ws_size,
                              hipStream_t stream) {
  const float* x    = (const float*)d_in[0];
  const int* ei     = (const int*)d_in[1];
  const int* batch  = (const int*)d_in[2];
  const float* W1   = (const float*)d_in[3];
  const float* b1   = (const float*)d_in[4];
  const float* W2   = (const float*)d_in[5];
  const float* b2   = (const float*)d_in[6];
  const int* srcp = ei;
  const int* dstp = ei + N_EDGES;
  float* out = (float*)d_out;

  // workspace carve (~24 MB)
  char* base = (char*)d_ws;
  size_t o = 0;
  auto carve = [&](size_t bytes) -> char* {
    char* p = base + o;
    o += (bytes + 255) & ~(size_t)255;
    return p;
  };
  int* bcnt       = (int*)carve((size_t)NB * 4);
  int* boffs      = (int*)carve((size_t)(NB + 1) * 4);
  int* blockBase  = (int*)carve((size_t)FILL_BLOCKS * NB * 4);
  unsigned* stage = (unsigned*)carve((size_t)N_EDGES * 4);
  float* dinv     = (float*)carve((size_t)N_NODES * 4);
  float* xd8      = (float*)carve((size_t)N_NODES * 8 * 4);
  float* g2       = (float*)carve((size_t)N_NODES * 8 * 4);
  float* gsum     = (float*)carve((size_t)N_GRAPHS * 8 * 4);

  hipMemsetAsync(bcnt, 0, (size_t)NB * 4, stream);
  hipMemsetAsync(gsum, 0, (size_t)N_GRAPHS * 8 * 4, stream);

  k_count<<<FILL_BLOCKS, 256, 0, stream>>>(dstp, bcnt, blockBase);
  k_bscan<<<1, 512, 0, stream>>>(bcnt, boffs);
  k_fill<<<FILL_BLOCKS, 256, 0, stream>>>(srcp, dstp, boffs, blockBase, stage);
  k_prep<<<NB, 256, 0, stream>>>(stage, boffs, x, dinv, xd8);
  k_agg1<<<NB, 256, 0, stream>>>(stage, boffs, xd8, dinv, W1, b1, W2, g2);
  k_agg2<<<NB, 256, 0, stream>>>(stage, boffs, g2, dinv, b2, batch, gsum);
  k_final<<<64, 256, 0, stream>>>(gsum, batch, out);
}

// Round 8
// 355.168 us; speedup vs baseline: 1.1478x; 1.1478x over previous
//
#include <hip/hip_runtime.h>

#define N_NODES 100000
#define N_EDGES 3200000
#define N_GRAPHS 2048
#define BSH 6                       // 64 nodes per bucket
#define BSZ 64
#define NB 1563                     // ceil(N_NODES/64)
#define FILL_BLOCKS 512
#define CHUNK 6250                  // N_EDGES / FILL_BLOCKS exactly

// global fp32 fadd (no CAS loop) — ONLY for global pointers
__device__ __forceinline__ void gAtomAdd(float* p, float v) {
  unsafeAtomicAdd(p, v);
}

// ---------- pass 1: per-block bucket histogram + space reservation ----------
__global__ void k_count(const int* __restrict__ dst, int* __restrict__ bcnt,
                        int* __restrict__ blockBase) {
  __shared__ int hist[NB];
  int tid = threadIdx.x, blk = blockIdx.x;
  for (int i = tid; i < NB; i += 256) hist[i] = 0;
  __syncthreads();
  int beg = blk * CHUNK, end = beg + CHUNK;
  for (int e = beg + tid; e < end; e += 256) atomicAdd(&hist[dst[e] >> BSH], 1);
  __syncthreads();
  for (int i = tid; i < NB; i += 256) {
    int h = hist[i];
    if (h) blockBase[blk * NB + i] = atomicAdd(&bcnt[i], h);
  }
}

// ---------- exclusive scan over NB bucket counts (single block, chunked) ----------
__global__ void k_bscan(const int* __restrict__ bcnt, int* __restrict__ boffs) {
  __shared__ int sh[512];
  __shared__ int carry;
  int tid = threadIdx.x;
  if (tid == 0) carry = 0;
  __syncthreads();
  for (int c = 0; c < NB; c += 512) {
    int i = c + tid;
    int v = (i < NB) ? bcnt[i] : 0;
    sh[tid] = v;
    __syncthreads();
    for (int off = 1; off < 512; off <<= 1) {
      int t = (tid >= off) ? sh[tid - off] : 0;
      __syncthreads();
      sh[tid] += t;
      __syncthreads();
    }
    if (i < NB) boffs[i] = carry + sh[tid] - v;
    __syncthreads();
    if (tid == 511) carry += sh[511];
    __syncthreads();
  }
  if (tid == 0) boffs[NB] = N_EDGES;
}

// ---------- pass 2: write packed edges into reserved dense sub-ranges ----------
__global__ void k_fill(const int* __restrict__ src, const int* __restrict__ dst,
                       const int* __restrict__ boffs, const int* __restrict__ blockBase,
                       unsigned* __restrict__ stage) {
  __shared__ int lbase[NB];
  int tid = threadIdx.x, blk = blockIdx.x;
  for (int i = tid; i < NB; i += 256) lbase[i] = boffs[i] + blockBase[blk * NB + i];
  __syncthreads();
  int beg = blk * CHUNK, end = beg + CHUNK;
  for (int e = beg + tid; e < end; e += 256) {
    int d = dst[e], s = src[e];
    int pos = atomicAdd(&lbase[d >> BSH], 1);   // LDS cursor
    stage[pos] = ((unsigned)s << BSH) | (unsigned)(d & (BSZ - 1));
  }
}

// ---------- bucket-local degree -> dinv, xd8 = x*dinv (padded to 8 floats/row) ----------
__global__ void k_prep(const unsigned* __restrict__ stage, const int* __restrict__ boffs,
                       const float* __restrict__ x, float* __restrict__ dinv,
                       float* __restrict__ xd8) {
  __shared__ int cnt[BSZ];
  int b = blockIdx.x, tid = threadIdx.x;
  if (tid < BSZ) cnt[tid] = 0;
  __syncthreads();
  int beg = boffs[b], end = boffs[b + 1];
  for (int k = beg + tid; k < end; k += 256) atomicAdd(&cnt[stage[k] & (BSZ - 1)], 1);
  __syncthreads();
  int node = b * BSZ + tid;
  if (tid < BSZ && node < N_NODES) {
    float di = rsqrtf((float)(cnt[tid] + 1));     // +1 self-loop; always > 0
    dinv[node] = di;
    float r[5];
#pragma unroll
    for (int c = 0; c < 5; c++) r[c] = x[node * 5 + c] * di;
    float4* xv = (float4*)xd8;
    xv[node * 2]     = make_float4(r[0], r[1], r[2], r[3]);
    xv[node * 2 + 1] = make_float4(r[4], 0.f, 0.f, 0.f);   // pad cols 5..7 = 0
  }
}

// ---------- layer-1 aggregation: 1 lane = 1 edge (32 edges/instr) + fused MLP ----------
__global__ void k_agg1(const unsigned* __restrict__ stage, const int* __restrict__ boffs,
                       const float* __restrict__ xd8, const float* __restrict__ dinv,
                       const float* __restrict__ W1, const float* __restrict__ b1,
                       const float* __restrict__ W2, float* __restrict__ g2) {
  __shared__ float acc[BSZ * 9];                  // stride 9: gcd(9,32)=1, banks spread
  __shared__ float w1[150], bb1[30], w2[240];
  int b = blockIdx.x, tid = threadIdx.x;
  for (int i = tid; i < BSZ * 9; i += 256) acc[i] = 0.f;
  for (int i = tid; i < 150; i += 256) w1[i] = W1[i];
  for (int i = tid; i < 30; i += 256) bb1[i] = b1[i];
  for (int i = tid; i < 240; i += 256) w2[i] = W2[i];
  __syncthreads();
  int beg = boffs[b], end = boffs[b + 1];
  for (int k0 = beg; k0 < end; k0 += 256) {
    int k = k0 + tid;
    int kk = (k < end) ? k : (end - 1);           // end > beg when loop entered
    unsigned u = stage[kk];
    const float* rp = xd8 + (u >> BSH) * 8;
    float4 lo = *(const float4*)rp;               // cols 0..3 (one line, 32B-aligned row)
    float c4 = rp[4];                             // col 4
    if (k < end) {
      float* a = acc + (u & (BSZ - 1)) * 9;
      atomicAdd(a + 0, lo.x); atomicAdd(a + 1, lo.y);
      atomicAdd(a + 2, lo.z); atomicAdd(a + 3, lo.w);
      atomicAdd(a + 4, c4);
    }
  }
  __syncthreads();
  int node = b * BSZ + tid;
  if (tid < BSZ && node < N_NODES) {
    float di = dinv[node];
    float t[5];
#pragma unroll
    for (int c = 0; c < 5; c++) t[c] = (acc[tid * 9 + c] + xd8[node * 8 + c]) * di;
    float h[30];
#pragma unroll
    for (int j = 0; j < 30; j++) h[j] = bb1[j];
#pragma unroll
    for (int kk = 0; kk < 5; kk++)
#pragma unroll
      for (int j = 0; j < 30; j++) h[j] += t[kk] * w1[kk * 30 + j];
    float g[8] = {0, 0, 0, 0, 0, 0, 0, 0};
#pragma unroll
    for (int j = 0; j < 30; j++) {
      float hj = fmaxf(h[j], 0.f);
#pragma unroll
      for (int c = 0; c < 8; c++) g[c] += hj * w2[j * 8 + c];
    }
    float4* gv = (float4*)g2;
    gv[node * 2]     = make_float4(g[0] * di, g[1] * di, g[2] * di, g[3] * di);
    gv[node * 2 + 1] = make_float4(g[4] * di, g[5] * di, g[6] * di, g[7] * di);
  }
}

// ---------- layer-2 aggregation: 1 lane = 1 edge (32 edges/instr) + fused pooling ----------
__global__ void k_agg2(const unsigned* __restrict__ stage, const int* __restrict__ boffs,
                       const float* __restrict__ g2, const float* __restrict__ dinv,
                       const float* __restrict__ b2, const int* __restrict__ batch,
                       float* __restrict__ gsum) {
  __shared__ float acc[BSZ * 9];                  // stride 9 breaks bank aliasing
  __shared__ float gpool[BSZ * 8];
  __shared__ float bb2[8];
  __shared__ int batch0s;
  int b = blockIdx.x, tid = threadIdx.x;
  for (int i = tid; i < BSZ * 9; i += 256) acc[i] = 0.f;
  for (int i = tid; i < BSZ * 8; i += 256) gpool[i] = 0.f;
  if (tid < 8) bb2[tid] = b2[tid];
  if (tid == 0) batch0s = batch[b * BSZ];
  __syncthreads();
  int beg = boffs[b], end = boffs[b + 1];
  for (int k0 = beg; k0 < end; k0 += 256) {
    int k = k0 + tid;
    int kk = (k < end) ? k : (end - 1);
    unsigned u = stage[kk];
    const float4* rp = (const float4*)(g2 + (u >> BSH) * 8);
    float4 lo = rp[0];                            // 32B row never straddles a 64B line
    float4 hi = rp[1];
    if (k < end) {
      float* a = acc + (u & (BSZ - 1)) * 9;
      atomicAdd(a + 0, lo.x); atomicAdd(a + 1, lo.y);
      atomicAdd(a + 2, lo.z); atomicAdd(a + 3, lo.w);
      atomicAdd(a + 4, hi.x); atomicAdd(a + 5, hi.y);
      atomicAdd(a + 6, hi.z); atomicAdd(a + 7, hi.w);
    }
  }
  __syncthreads();
  int node = b * BSZ + tid;
  int batch0 = batch0s;
  if (tid < BSZ && node < N_NODES) {
    float di = dinv[node];
    int goff = batch[node] - batch0;
#pragma unroll
    for (int c = 0; c < 8; c++) {
      float val = di * (g2[node * 8 + c] + acc[tid * 9 + c]) + bb2[c];
      if (goff < BSZ) atomicAdd(&gpool[goff * 8 + c], val);
      else            gAtomAdd(&gsum[batch[node] * 8 + c], val);
    }
  }
  __syncthreads();
  for (int i = tid; i < BSZ * 8; i += 256) {
    int gid = batch0 + (i >> 3);
    float v = gpool[i];
    if (gid < N_GRAPHS && v != 0.f) gAtomAdd(&gsum[gid * 8 + (i & 7)], v);
  }
}

// ---------- epilogue: divide by per-graph node count (binary search, batch sorted) ----------
__global__ void k_final(const float* __restrict__ gsum, const int* __restrict__ batch,
                        float* __restrict__ out) {
  int i = blockIdx.x * 256 + threadIdx.x;
  if (i >= N_GRAPHS * 8) return;
  int g = i >> 3;
  int lo = 0, hi = N_NODES;
  while (lo < hi) { int m = (lo + hi) >> 1; if (batch[m] < g) lo = m + 1; else hi = m; }
  int lo2 = lo, hi2 = N_NODES;
  while (lo2 < hi2) { int m = (lo2 + hi2) >> 1; if (batch[m] <= g) lo2 = m + 1; else hi2 = m; }
  float c = (float)(lo2 - lo);
  out[i] = gsum[i] / fmaxf(c, 1.f);
}

extern "C" void kernel_launch(void* const* d_in, const int* in_sizes, int n_in,
                              void* d_out, int out_size, void* d_ws, size_t ws_size,
                              hipStream_t stream) {
  const float* x    = (const float*)d_in[0];
  const int* ei     = (const int*)d_in[1];
  const int* batch  = (const int*)d_in[2];
  const float* W1   = (const float*)d_in[3];
  const float* b1   = (const float*)d_in[4];
  const float* W2   = (const float*)d_in[5];
  const float* b2   = (const float*)d_in[6];
  const int* srcp = ei;
  const int* dstp = ei + N_EDGES;
  float* out = (float*)d_out;

  // workspace carve (~24 MB)
  char* base = (char*)d_ws;
  size_t o = 0;
  auto carve = [&](size_t bytes) -> char* {
    char* p = base + o;
    o += (bytes + 255) & ~(size_t)255;
    return p;
  };
  int* bcnt       = (int*)carve((size_t)NB * 4);
  int* boffs      = (int*)carve((size_t)(NB + 1) * 4);
  int* blockBase  = (int*)carve((size_t)FILL_BLOCKS * NB * 4);
  unsigned* stage = (unsigned*)carve((size_t)N_EDGES * 4);
  float* dinv     = (float*)carve((size_t)N_NODES * 4);
  float* xd8      = (float*)carve((size_t)N_NODES * 8 * 4);
  float* g2       = (float*)carve((size_t)N_NODES * 8 * 4);
  float* gsum     = (float*)carve((size_t)N_GRAPHS * 8 * 4);

  hipMemsetAsync(bcnt, 0, (size_t)NB * 4, stream);
  hipMemsetAsync(gsum, 0, (size_t)N_GRAPHS * 8 * 4, stream);

  k_count<<<FILL_BLOCKS, 256, 0, stream>>>(dstp, bcnt, blockBase);
  k_bscan<<<1, 512, 0, stream>>>(bcnt, boffs);
  k_fill<<<FILL_BLOCKS, 256, 0, stream>>>(srcp, dstp, boffs, blockBase, stage);
  k_prep<<<NB, 256, 0, stream>>>(stage, boffs, x, dinv, xd8);
  k_agg1<<<NB, 256, 0, stream>>>(stage, boffs, xd8, dinv, W1, b1, W2, g2);
  k_agg2<<<NB, 256, 0, stream>>>(stage, boffs, g2, dinv, b2, batch, gsum);
  k_final<<<64, 256, 0, stream>>>(gsum, batch, out);
}